// Round 12
// baseline (327.548 us; speedup 1.0000x reference)
//
#include <hip/hip_runtime.h>
#include <hip/hip_bf16.h>
#include <stdint.h>

typedef unsigned short ushort_t;
typedef __attribute__((ext_vector_type(8))) __bf16 bf16x8;
typedef __attribute__((ext_vector_type(8))) short short8;
typedef __attribute__((ext_vector_type(4))) float f32x4;
typedef __attribute__((ext_vector_type(4))) unsigned int uint4v;

// ---- helpers ----------------------------------------------------------------
__device__ __forceinline__ ushort_t f2b(float f) {  // fp32 -> bf16 (RNE)
  union { float f; uint32_t u; } c; c.f = f;
  return (ushort_t)((c.u + 0x7fffu + ((c.u >> 16) & 1u)) >> 16);
}
__device__ __forceinline__ float b2f(ushort_t b) {
  union { float f; uint32_t u; } c; c.u = ((uint32_t)b) << 16;
  return c.f;
}
__device__ __forceinline__ float dot2bf(uint32_t qu, uint32_t ku, float acc) {
  union { uint32_t u; float f; } a, b, c, d;
  a.u = qu << 16; b.u = qu & 0xffff0000u;
  c.u = ku << 16; d.u = ku & 0xffff0000u;
  acc = fmaf(a.f, c.f, acc);
  return fmaf(b.f, d.f, acc);
}

// ---- elementwise f32 -> bf16 ------------------------------------------------
__global__ __launch_bounds__(256) void f32_to_b16(
    const float* __restrict__ in, ushort_t* __restrict__ out) {
  const int i = (blockIdx.x * 256 + threadIdx.x) * 8;
  const f32x4 a = *(const f32x4*)&in[i];
  const f32x4 b = *(const f32x4*)&in[i + 4];
  short8 t;
#pragma unroll
  for (int j = 0; j < 4; j++) { t[j] = (short)f2b(a[j]); t[4 + j] = (short)f2b(b[j]); }
  *(short8*)&out[i] = t;
}

// ---- transpose f32 [K][N] -> bf16 [N][K] ------------------------------------
__global__ __launch_bounds__(256) void transpose_f2b(
    const float* __restrict__ in, ushort_t* __restrict__ out, int K, int N) {
  __shared__ __align__(16) ushort_t tile[64][72];
  const int k0 = blockIdx.x * 64, n0 = blockIdx.y * 64;
  const int tid = threadIdx.x;
#pragma unroll
  for (int i = 0; i < 4; i++) {
    const int idx = i * 256 + tid;
    const int r = idx >> 4, c = (idx & 15) * 4;
    const f32x4 a = *(const f32x4*)&in[(size_t)(k0 + r) * N + n0 + c];
#pragma unroll
    for (int j = 0; j < 4; j++) tile[r][c + j] = f2b(a[j]);
  }
  __syncthreads();
#pragma unroll
  for (int i = 0; i < 16; i++) {
    const int idx = i * 256 + tid;
    const int r = idx >> 6, c = idx & 63;
    out[(size_t)(n0 + r) * K + k0 + c] = tile[c][r];
  }
}

// ---- GEMM: C[M,N] = A[M,K](bf16) * Bt[N,K]^T(bf16) + bias -------------------
// MODE 0: scatter bf16 into q/k/v [B,H,T,D].  MODE 1: f32 row-major out.
// Staging via global_load_lds dwordx4 (LDS dest = base + lane*16, rows 128 B).
// XCD-confining swizzle: each XCD owns 8 consecutive row-panels so the 2 MB
// A chunk stays L2-resident while B streams. Requires gridDim.y==64.
// MODE 0 epilogue (r12): stage f2b(acc+bias) into the dead Als/Bls 32 KB as a
// [128][128] bf16 tile (XOR-swizzled, bank-clean), then write each head-half
// as a 16 KB CONTIGUOUS burst (8 x short8/thread) -- replaces 64 scattered
// 2 B stores/thread.
template <int MODE>
__global__ __launch_bounds__(256) void gemm_bt(
    const ushort_t* __restrict__ A, const ushort_t* __restrict__ Bt,
    const float* __restrict__ bias,
    ushort_t* __restrict__ q_out, ushort_t* __restrict__ k_out,
    ushort_t* __restrict__ v_out, float* __restrict__ f_out,
    int M, int N, int K) {
  __shared__ __align__(16) ushort_t gls[16384];  // Als | Bls, contiguous 32 KB
  ushort_t* Als = gls;
  ushort_t* Bls = gls + 8192;
  const int tid = threadIdx.x;
  const int wave = tid >> 6, lane = tid & 63;
  const int quad = lane >> 4, l15 = lane & 15;
  const int wr = wave >> 1, wc = wave & 1;
  // bijective XCD remap (nbx*64 % 8 == 0 for both grids: 24x64, 8x64)
  const int linear = (int)blockIdx.x + (int)gridDim.x * (int)blockIdx.y;
  const int xcd = linear & 7, chunk = linear >> 3;
  const int by = xcd * 8 + (chunk & 7);   // 8 row-panels per XCD
  const int bx = chunk >> 3;
  const int rowBase = by * 128;
  const int colBase = bx * 128;
  const f32x4 fzero = {0.f, 0.f, 0.f, 0.f};

  f32x4 acc[4][4];
#pragma unroll
  for (int mi = 0; mi < 4; mi++)
#pragma unroll
    for (int ni = 0; ni < 4; ni++) acc[mi][ni] = fzero;

  const int srow = tid >> 3;       // 0..31
  const int scol = (tid & 7) * 8;  // 0,8,...,56 (elements)

  for (int kk = 0; kk < K; kk += 64) {
    __syncthreads();
#pragma unroll
    for (int s = 0; s < 4; s++) {
      const int r = s * 32 + srow;
      __builtin_amdgcn_global_load_lds(
          (const __attribute__((address_space(1))) unsigned int*)
              &A[(size_t)(rowBase + r) * K + kk + scol],
          (__attribute__((address_space(3))) unsigned int*)&Als[r * 64 + scol],
          16, 0, 0);
      __builtin_amdgcn_global_load_lds(
          (const __attribute__((address_space(1))) unsigned int*)
              &Bt[(size_t)(colBase + r) * K + kk + scol],
          (__attribute__((address_space(3))) unsigned int*)&Bls[r * 64 + scol],
          16, 0, 0);
    }
    __syncthreads();
#pragma unroll
    for (int ks = 0; ks < 2; ks++) {
      const int ko = ks * 32 + quad * 8;
      bf16x8 af[4], bfr[4];
#pragma unroll
      for (int mi = 0; mi < 4; mi++)
        af[mi] = *(const bf16x8*)&Als[(wr * 64 + mi * 16 + l15) * 64 + ko];
#pragma unroll
      for (int ni = 0; ni < 4; ni++)
        bfr[ni] = *(const bf16x8*)&Bls[(wc * 64 + ni * 16 + l15) * 64 + ko];
#pragma unroll
      for (int mi = 0; mi < 4; mi++)
#pragma unroll
        for (int ni = 0; ni < 4; ni++)
          acc[mi][ni] = __builtin_amdgcn_mfma_f32_16x16x32_bf16(
              af[mi], bfr[ni], acc[mi][ni], 0, 0, 0);
    }
  }

  if (MODE == 0) {
    __syncthreads();  // all waves done with Als/Bls reads
#pragma unroll
    for (int mi = 0; mi < 4; mi++) {
      const int rl = wr * 64 + mi * 16 + quad * 4;
#pragma unroll
      for (int ni = 0; ni < 4; ni++) {
        const int cl = wc * 64 + ni * 16 + l15;
        const float bv = bias[colBase + cl];
#pragma unroll
        for (int r = 0; r < 4; r++) {
          const int row = rl + r;
          gls[row * 128 + (cl ^ ((row & 7) << 3))] = f2b(acc[mi][ni][r] + bv);
        }
      }
    }
    __syncthreads();
    const int which = colBase >> 10;
    ushort_t* dst = which == 0 ? q_out : (which == 1 ? k_out : v_out);
    const int h0 = (colBase & 1023) >> 6;
    const int bidx = rowBase >> 12, t0 = rowBase & 4095;
#pragma unroll
    for (int half = 0; half < 2; half++) {
      ushort_t* dstp = dst + ((size_t)(bidx * 16 + h0 + half) * 4096 + t0) * 64;
#pragma unroll
      for (int p = 0; p < 4; p++) {
        const int elem = (p * 256 + tid) * 8;       // 0..8191
        const int tl = elem >> 6, d = elem & 63;
        *(short8*)&dstp[elem] =
            *(short8*)&gls[tl * 128 + ((half * 64 + d) ^ ((tl & 7) << 3))];
      }
    }
  } else {
#pragma unroll
    for (int mi = 0; mi < 4; mi++) {
#pragma unroll
      for (int ni = 0; ni < 4; ni++) {
        const int col = colBase + wc * 64 + ni * 16 + l15;
        const float bv = bias[col];
#pragma unroll
        for (int r = 0; r < 4; r++) {
          const int row = rowBase + wr * 64 + mi * 16 + quad * 4 + r;
          f_out[(size_t)row * N + col] = acc[mi][ni][r] + bv;
        }
      }
    }
  }
}

// ---- sparse flash attention v13 ---------------------------------------------
// v13 = v12 (r11 winner: 106.5 us, dual-q-tile 512-thread blocks, XCD-confined)
// + LDS-staged coalesced Y write: each wave stages its 16x64 output into its
// dead Pw region (stride 68, bank-clean), then writes 128 B-contiguous rows
// (2 x short8/thread) -- replaces 16 scattered 2 B stores/thread.
#define LP 72
__global__ __launch_bounds__(512) void sparse_attn(
    const ushort_t* __restrict__ Qb, const ushort_t* __restrict__ Kb,
    const ushort_t* __restrict__ Vb, ushort_t* __restrict__ Y) {
  __shared__ __align__(16) ushort_t Qls[128 * LP];
  // K | Vt | P regions; whole region reused as f32 merge scratch after the
  // last dense tile (8 waves x 16 x 68 f32 = 34816 B <= 36864 B).
  __shared__ __align__(16) char smem[(64 * LP + 64 * LP + 128 * LP) * 2];
  ushort_t* Kls = (ushort_t*)smem;
  ushort_t* Vtls = Kls + 64 * LP;
  ushort_t* Pls = Vtls + 64 * LP;

  const int tid = threadIdx.x;
  const int wave = tid >> 6, lane = tid & 63;
  const int quad = lane >> 4, l15 = lane & 15;
  const int wq = wave >> 2, wl = wave & 3;  // q-tile group, wave-in-group

  // XCD-confining + LPT remap: xcd = linear%8 owns 4 head-pairs; within an
  // XCD, pair-index descending (heaviest q-tiles of all its heads first).
  const int linear = (int)blockIdx.x + 32 * (int)blockIdx.y + 512 * (int)blockIdx.z;
  const int xcd = linear & 7, slot = linear >> 3;   // slot 0..127
  const int pr = xcd * 4 + (slot & 3);              // (b*16+h) index 0..31
  const int q0t = 2 * (31 - (slot >> 2));           // even q-tile, heavy first
  const int q1t = q0t + 1;
  const int h = pr & 15, b = pr >> 4;
  const int q0 = (q0t + wq) * 64;                   // this wave-group's q-base
  const size_t headoff = (size_t)pr * 4096 * 64;
  const ushort_t* Qp = Qb + headoff;
  const ushort_t* Kp = Kb + headoff;
  const ushort_t* Vp = Vb + headoff;
  const f32x4 fzero = {0.f, 0.f, 0.f, 0.f};
  const float scale = 0.125f;

#pragma unroll
  for (int i = 0; i < 2; i++) {  // stage Q: 128 contiguous rows (both q-tiles)
    const int idx = i * 512 + tid;
    const int r = idx >> 3, c = (idx & 7) * 8;
    *(short8*)&Qls[r * LP + c] = *(const short8*)&Qp[(size_t)(q0t * 64 + r) * 64 + c];
  }
  __syncthreads();
  bf16x8 qf[2];
#pragma unroll
  for (int ks = 0; ks < 2; ks++)
    qf[ks] = *(const bf16x8*)&Qls[(wq * 64 + wl * 16 + l15) * LP + ks * 32 + quad * 8];

  f32x4 o[4];
#pragma unroll
  for (int dt = 0; dt < 4; dt++) o[dt] = fzero;
  float mrun[4], lsum[4];
#pragma unroll
  for (int r = 0; r < 4; r++) { mrun[r] = -1e30f; lsum[r] = 0.f; }
  ushort_t* Pw = &Pls[wave * 16 * LP];

  // mode: -1=skip, 0=no mask, 1=causal only, 2=dist<256||dist%128==0, 3=full
  auto dense_tile = [&](int k0, int modeA, int modeB) {
    const int mode = (wq == 0) ? modeA : modeB;
    __syncthreads();  // prior tile's LDS reads complete
    {  // K [key][d]: 512 threads cover 64 rows x 8 chunks in one pass
      const int r = tid >> 3, c = (tid & 7) * 8;
      *(short8*)&Kls[r * LP + c] = *(const short8*)&Kp[(size_t)(k0 + r) * 64 + c];
    }
    {  // V transposed [d][key]: one short8 per thread
      const int key = tid & 63, dblk = (tid >> 6) * 8;
      short8 vv = *(const short8*)&Vp[(size_t)(k0 + key) * 64 + dblk];
#pragma unroll
      for (int m = 0; m < 8; m++) Vtls[(dblk + m) * LP + key] = (ushort_t)vv[m];
    }
    __syncthreads();  // staging visible

    float p[4][4];
    if (mode >= 0) {
      f32x4 sacc[4];
#pragma unroll
      for (int ni = 0; ni < 4; ni++) sacc[ni] = fzero;
#pragma unroll
      for (int ks = 0; ks < 2; ks++) {
        const int ko = ks * 32 + quad * 8;
#pragma unroll
        for (int ni = 0; ni < 4; ni++) {
          bf16x8 kf = *(const bf16x8*)&Kls[(ni * 16 + l15) * LP + ko];
          sacc[ni] = __builtin_amdgcn_mfma_f32_16x16x32_bf16(qf[ks], kf, sacc[ni], 0, 0, 0);
        }
      }

      const int i0 = q0 + wl * 16 + quad * 4;
      if (mode == 0) {
#pragma unroll
        for (int ni = 0; ni < 4; ni++)
#pragma unroll
          for (int r = 0; r < 4; r++) p[ni][r] = sacc[ni][r] * scale;
      } else {
#pragma unroll
        for (int ni = 0; ni < 4; ni++) {
          const int j = k0 + ni * 16 + l15;
#pragma unroll
          for (int r = 0; r < 4; r++) {
            const int dist = i0 + r - j;
            bool ok;
            if (mode == 1)      ok = dist >= 0;
            else if (mode == 2) ok = (dist < 256) || ((dist & 127) == 0);
            else                ok = (dist >= 0) &&
                                     ((dist < 256) || ((dist & 127) == 0) || (j < 16));
            p[ni][r] = ok ? sacc[ni][r] * scale : -1e30f;
          }
        }
      }

      float alpha[4];
#pragma unroll
      for (int r = 0; r < 4; r++) {
        float m = fmaxf(fmaxf(p[0][r], p[1][r]), fmaxf(p[2][r], p[3][r]));
        m = fmaxf(m, __shfl_xor(m, 1));
        m = fmaxf(m, __shfl_xor(m, 2));
        m = fmaxf(m, __shfl_xor(m, 4));
        m = fmaxf(m, __shfl_xor(m, 8));
        const float mnew = fmaxf(mrun[r], m);
        alpha[r] = __expf(mrun[r] - mnew);
        mrun[r] = mnew;
        float rs = 0.f;
#pragma unroll
        for (int ni = 0; ni < 4; ni++) {
          const float e = __expf(p[ni][r] - mnew);
          p[ni][r] = e;
          rs += e;
        }
        rs += __shfl_xor(rs, 1);
        rs += __shfl_xor(rs, 2);
        rs += __shfl_xor(rs, 4);
        rs += __shfl_xor(rs, 8);
        lsum[r] = lsum[r] * alpha[r] + rs;
      }
#pragma unroll
      for (int dt = 0; dt < 4; dt++)
#pragma unroll
        for (int r = 0; r < 4; r++) o[dt][r] *= alpha[r];

#pragma unroll
      for (int ni = 0; ni < 4; ni++)
#pragma unroll
        for (int r = 0; r < 4; r++)
          Pw[(quad * 4 + r) * LP + ni * 16 + l15] = f2b(p[ni][r]);
    }
    __syncthreads();  // unconditional: all 8 waves rendezvous

    if (mode >= 0) {
#pragma unroll
      for (int ks = 0; ks < 2; ks++) {
        const int ko = ks * 32 + quad * 8;
        bf16x8 pf = *(const bf16x8*)&Pw[l15 * LP + ko];
#pragma unroll
        for (int dt = 0; dt < 4; dt++) {
          bf16x8 vf = *(const bf16x8*)&Vtls[(dt * 16 + l15) * LP + ko];
          o[dt] = __builtin_amdgcn_mfma_f32_16x16x32_bf16(pf, vf, o[dt], 0, 0, 0);
        }
      }
    }
  };

  if (q1t < 6) {
    // light pairs (q0t in {0,2,4}): all tiles full-mask; A skips kt>q0t
    for (int kt = 0; kt <= q1t; kt++)
      dense_tile(kt * 64, kt <= q0t ? 3 : -1, 3);
  } else {
    dense_tile(0, 3, 3);  // global + in-tile strided for both groups
    for (int kt = q0t - 4; kt <= q0t + 1; kt++) {
      const int mA = (kt == q0t - 4) ? 2
                   : (kt < q0t) ? 0 : (kt == q0t) ? 1 : -1;
      const int mB = (kt == q0t - 4) ? -1
                   : (kt == q0t - 3) ? 2 : (kt <= q0t) ? 0 : 1;
      dense_tile(kt * 64, mA, mB);
    }

    // ---- strided phase: per-wave, barrier-free, register-resident ----------
    // key j = i - 128s, blocks [k0s, k0s+64), k0s >= 64. Lane (quad,l15)
    // owns q/key row (wl*16+l15) of its group's q-tile, dims quad*16..+16.
    const int rowl = wl * 16 + l15;
    const uint4v qv0 = *(const uint4v*)&Qls[(wq * 64 + rowl) * LP + quad * 16];
    const uint4v qv1 = *(const uint4v*)&Qls[(wq * 64 + rowl) * LP + quad * 16 + 8];
    const ushort_t* Kr = Kp + (size_t)rowl * 64 + quad * 16;
    const ushort_t* Vr = Vp + (size_t)rowl * 64 + quad * 16;

    float ms = -1e30f, ls = 0.f;
    f32x4 os4[4];
#pragma unroll
    for (int c = 0; c < 4; c++) os4[c] = fzero;

    auto sproc = [&](uint4v ka0, uint4v ka1, uint4v va0, uint4v va1) {
      float sd = 0.f;
#pragma unroll
      for (int m2 = 0; m2 < 4; m2++) {
        sd = dot2bf(qv0[m2], ka0[m2], sd);
        sd = dot2bf(qv1[m2], ka1[m2], sd);
      }
      sd += __shfl_xor(sd, 16);
      sd += __shfl_xor(sd, 32);
      const float sig = sd * scale;
      const float mnew = fmaxf(ms, sig);
      const float al = __expf(ms - mnew);
      const float e = __expf(sig - mnew);
      ms = mnew;
      ls = ls * al + e;
#pragma unroll
      for (int m2 = 0; m2 < 4; m2++) {
        union { uint32_t u; float f; } va, vb, vc, vd;
        va.u = va0[m2] << 16;          // dim 2*m2
        vb.u = va0[m2] & 0xffff0000u;  // dim 2*m2+1
        vc.u = va1[m2] << 16;          // dim 8+2*m2
        vd.u = va1[m2] & 0xffff0000u;  // dim 8+2*m2+1
        const int d0 = 2 * m2, d1 = 2 * m2 + 1;
        os4[d0 >> 2][d0 & 3] = fmaf(os4[d0 >> 2][d0 & 3], al, e * va.f);
        os4[d1 >> 2][d1 & 3] = fmaf(os4[d1 >> 2][d1 & 3], al, e * vb.f);
        os4[(d0 + 8) >> 2][d0 & 3] = fmaf(os4[(d0 + 8) >> 2][d0 & 3], al, e * vc.f);
        os4[(d1 + 8) >> 2][d1 & 3] = fmaf(os4[(d1 + 8) >> 2][d1 & 3], al, e * vd.f);
      }
    };

    int k0s = q0 - 384;
    if (k0s >= 64) {
      uint4v ka0 = *(const uint4v*)(Kr + (size_t)k0s * 64);
      uint4v ka1 = *(const uint4v*)(Kr + (size_t)k0s * 64 + 8);
      uint4v va0 = *(const uint4v*)(Vr + (size_t)k0s * 64);
      uint4v va1 = *(const uint4v*)(Vr + (size_t)k0s * 64 + 8);
      while (true) {
        const int nxt = k0s - 128;
        uint4v kb0, kb1, vb0, vb1;
        if (nxt >= 64) {  // depth-1 prefetch: L2-hit latency hides under sproc
          kb0 = *(const uint4v*)(Kr + (size_t)nxt * 64);
          kb1 = *(const uint4v*)(Kr + (size_t)nxt * 64 + 8);
          vb0 = *(const uint4v*)(Vr + (size_t)nxt * 64);
          vb1 = *(const uint4v*)(Vr + (size_t)nxt * 64 + 8);
        }
        sproc(ka0, ka1, va0, va1);
        if (nxt < 64) break;
        ka0 = kb0; ka1 = kb1; va0 = vb0; va1 = vb1;
        k0s = nxt;
      }
    }

    // ---- merge strided state into dense state (once per block) -------------
    // scratch aliases K/Vt/P: every wave must be past its dense-tile LDS reads.
    __syncthreads();
    float* scr = (float*)smem + wave * (16 * 68);  // per-wave [16][68] f32
#pragma unroll
    for (int c = 0; c < 4; c++)
      *(f32x4*)&scr[l15 * 68 + quad * 16 + c * 4] = os4[c];
    asm volatile("s_waitcnt lgkmcnt(0)" ::: "memory");
    __builtin_amdgcn_wave_barrier();
#pragma unroll
    for (int r = 0; r < 4; r++) {
      const float ms_r = __shfl(ms, quad * 4 + r);
      const float ls_r = __shfl(ls, quad * 4 + r);
      const float M = fmaxf(mrun[r], ms_r);
      const float ea = __expf(mrun[r] - M);
      const float eb = __expf(ms_r - M);  // == 0 when no strided levels ran
      lsum[r] = lsum[r] * ea + ls_r * eb;
#pragma unroll
      for (int dt = 0; dt < 4; dt++)
        o[dt][r] = o[dt][r] * ea + scr[(quad * 4 + r) * 68 + dt * 16 + l15] * eb;
    }
  }

  // ---- LDS-staged coalesced Y write ----------------------------------------
  // Wave stages its 16x64 output into its own Pw region (stride 68, bank-
  // clean), then writes 128 B-contiguous rows. Block barrier first: Pw may
  // overlap another wave's merge-scratch region.
  __syncthreads();
  {
    ushort_t* Yw = Pw;
#pragma unroll
    for (int dt = 0; dt < 4; dt++)
#pragma unroll
      for (int r = 0; r < 4; r++)
        Yw[(quad * 4 + r) * 68 + dt * 16 + l15] = f2b(o[dt][r] / lsum[r]);
    asm volatile("s_waitcnt lgkmcnt(0)" ::: "memory");
    __builtin_amdgcn_wave_barrier();
    const size_t ybase = ((size_t)(b * 4096 + q0 + wl * 16)) * 1024 + h * 64;
#pragma unroll
    for (int p = 0; p < 2; p++) {
      const int rr = p * 8 + (lane >> 3);
      const int cc = (lane & 7) * 8;
      *(short8*)&Y[ybase + (size_t)rr * 1024 + cc] = *(short8*)&Yw[rr * 68 + cc];
    }
  }
}

// ---- launch -----------------------------------------------------------------
static const void* by_size(void* const* d_in, const int* in_sizes, int n_in,
                           int want, int fallback_idx) {
  for (int i = 0; i < n_in; i++)
    if (in_sizes[i] == want) return d_in[i];
  return d_in[fallback_idx];
}

extern "C" void kernel_launch(void* const* d_in, const int* in_sizes, int n_in,
                              void* d_out, int out_size, void* d_ws,
                              size_t ws_size, hipStream_t stream) {
  const float* x      = (const float*)by_size(d_in, in_sizes, n_in, 8388608, 0);
  const float* w_qkv  = (const float*)by_size(d_in, in_sizes, n_in, 3145728, 1);
  const float* b_qkv  = (const float*)by_size(d_in, in_sizes, n_in, 3072, 2);
  const float* w_proj = (const float*)by_size(d_in, in_sizes, n_in, 1048576, 3);
  const float* b_proj = (const float*)by_size(d_in, in_sizes, n_in, 1024, 4);
  float* out = (float*)d_out;                     // [2,4096,1024] f32
  char* ws = (char*)d_ws;
  ushort_t* wqkvT  = (ushort_t*)(ws);             //  6.3 MB bf16 [3072,1024]
  ushort_t* wprojT = (ushort_t*)(ws + 6291456);   //  2.1 MB bf16 [1024,1024]
  ushort_t* qb     = (ushort_t*)(ws + 8388608);   // 16.8 MB bf16 [B,H,T,D]
  ushort_t* kb     = (ushort_t*)(ws + 25165824);
  ushort_t* vb     = (ushort_t*)(ws + 41943040);
  ushort_t* yb     = (ushort_t*)(ws + 58720256);  // 16.8 MB bf16 [8192,1024]
  ushort_t* xb     = yb;  // x-bf16 aliases yb: dead before attention writes yb

  if (ws_size < 75497472) return;  // proven satisfied

  f32_to_b16<<<4096, 256, 0, stream>>>(x, xb);
  transpose_f2b<<<dim3(16, 48), 256, 0, stream>>>(w_qkv, wqkvT, 1024, 3072);
  transpose_f2b<<<dim3(16, 16), 256, 0, stream>>>(w_proj, wprojT, 1024, 1024);
  gemm_bt<0><<<dim3(24, 64), 256, 0, stream>>>(
      xb, wqkvT, b_qkv, qb, kb, vb, nullptr, 8192, 3072, 1024);
  sparse_attn<<<dim3(32, 16, 2), 512, 0, stream>>>(qb, kb, vb, yb);
  gemm_bt<1><<<dim3(8, 64), 256, 0, stream>>>(
      yb, wprojT, b_proj, nullptr, nullptr, nullptr, out, 8192, 1024, 1024);
}